// Round 4
// baseline (350.743 us; speedup 1.0000x reference)
//
#include <hip/hip_runtime.h>
#include <math.h>

// Problem dims (fixed): B=128, S=64, H=128, STATIC=DYNAMIC=2
// Outputs: tour_idx [B,S] (as f32), tour_logp [B,S] -> d_out 16384 f32

#define K1  1.44269504088896340736f   // log2(e)
#define K2  2.88539008177792681472f   // 2*log2(e)
#define LN2 0.69314718055994530942f

// ---------------- ws layout (float offsets) ----------------
#define WS_M     0                       // [384][2]   M = wih @ decoder_w
#define WS_C     768                     // [384]      c = wih @ decoder_b + bih
#define WS_PREA  1152                    // [B][128][64] EA = exp2(K2*(W1@sh + W2@dh))
#define WS_PREP  (WS_PREA + 128*8192)    // [B][128][64] EP = exp2(K2*(P1@sh))
#define WS_Q     (WS_PREP + 128*8192)    // [B][128][64] Q  = P2@sh

// LDS swizzles (conflict-free for the specific read patterns)
#define SW(h)   ((h) + ((h) >> 2))            // 128-vec read at stride 8
#define PADH(h) ((((h) >> 4) * 20) + ((h) & 15))  // 128-vec float4 read, 16-chunks

// ---- DPP cross-lane (VALU-speed; rows=16 lanes) ----
template <int CTRL>
__device__ __forceinline__ float dppf(float x) {
  int xi = __builtin_bit_cast(int, x);
  return __builtin_bit_cast(float,
      __builtin_amdgcn_update_dpp(xi, xi, CTRL, 0xF, 0xF, false));
}
template <int CTRL>
__device__ __forceinline__ int dppi(int x) {
  return __builtin_amdgcn_update_dpp(x, x, CTRL, 0xF, 0xF, false);
}
// 0xB1=quad xor1, 0x4E=quad xor2, 0x141=row_half_mirror (xor-ish 8), 0x128=row_ror:8
__device__ __forceinline__ float sum8(float x) {   // 8 consecutive lanes
  x += dppf<0xB1>(x); x += dppf<0x4E>(x); x += dppf<0x141>(x); return x;
}
__device__ __forceinline__ float sum16(float x) {  // 16 consecutive lanes
  x += dppf<0xB1>(x); x += dppf<0x4E>(x); x += dppf<0x141>(x); x += dppf<0x128>(x);
  return x;
}
__device__ __forceinline__ float sum64(float x) {
  x = sum16(x); x += __shfl_xor(x, 16); x += __shfl_xor(x, 32); return x;
}
__device__ __forceinline__ float max64(float x) {
  x = fmaxf(x, dppf<0xB1>(x)); x = fmaxf(x, dppf<0x4E>(x));
  x = fmaxf(x, dppf<0x141>(x)); x = fmaxf(x, dppf<0x128>(x));
  x = fmaxf(x, __shfl_xor(x, 16)); x = fmaxf(x, __shfl_xor(x, 32)); return x;
}
#define RCP(x)  __builtin_amdgcn_rcpf(x)
#define EXP2(x) __builtin_amdgcn_exp2f(x)

// ---------------- tiny precompute: GRU input-path folding ----------------
__global__ __launch_bounds__(256) void prep_small(
    const float* __restrict__ wih, const float* __restrict__ decw,
    const float* __restrict__ decb, const float* __restrict__ bih,
    float* __restrict__ ws) {
  int gid = blockIdx.x * 256 + threadIdx.x;
  if (gid < 384) {
    float m0 = 0.f, m1 = 0.f, cc = 0.f;
    for (int k = 0; k < 128; ++k) {
      float w = wih[gid * 128 + k];
      m0 += w * decw[k * 2 + 0];
      m1 += w * decw[k * 2 + 1];
      cc += w * decb[k];
    }
    ws[WS_M + gid * 2 + 0] = m0;
    ws[WS_M + gid * 2 + 1] = m1;
    ws[WS_C + gid] = cc + bih[gid];
  }
}

// ---------------- big precompute: EA / EP / Q per batch ------------------
__global__ __launch_bounds__(256) void prep_big(
    const float* __restrict__ statics, const float* __restrict__ dynamics,
    const float* __restrict__ sw, const float* __restrict__ sb,
    const float* __restrict__ dw, const float* __restrict__ db,
    const float* __restrict__ attn_W, const float* __restrict__ ptr_W,
    float* __restrict__ ws) {
  __shared__ __align__(16) float sh[128 * 64];
  __shared__ __align__(16) float dh[128 * 64];
  __shared__ float st[128];
  __shared__ float dy[128];
  int b = blockIdx.x >> 3;
  int hq = blockIdx.x & 7;
  int t = threadIdx.x;
  if (t < 128) st[t] = statics[b * 128 + t];
  else         dy[t - 128] = dynamics[b * 128 + (t - 128)];
  __syncthreads();
  for (int e = t; e < 8192; e += 256) {
    int h = e >> 6, s = e & 63;
    sh[e] = sw[h * 2 + 0] * st[s] + sw[h * 2 + 1] * st[64 + s] + sb[h];
    dh[e] = dw[h * 2 + 0] * dy[s] + dw[h * 2 + 1] * dy[64 + s] + db[h];
  }
  __syncthreads();
  int hh = hq * 16 + (t >> 4);
  int s0 = (t & 15) * 4;
  float4 pA = {0, 0, 0, 0}, pP = {0, 0, 0, 0}, qq = {0, 0, 0, 0};
  for (int k = 0; k < 128; ++k) {
    float4 sv = *(const float4*)&sh[k * 64 + s0];
    float4 dv = *(const float4*)&dh[k * 64 + s0];
    float w1 = attn_W[hh * 384 + k];
    float w2 = attn_W[hh * 384 + 128 + k];
    float p1 = ptr_W[hh * 256 + k];
    float p2 = ptr_W[hh * 256 + 128 + k];
    pA.x += w1 * sv.x + w2 * dv.x;  pA.y += w1 * sv.y + w2 * dv.y;
    pA.z += w1 * sv.z + w2 * dv.z;  pA.w += w1 * sv.w + w2 * dv.w;
    pP.x += p1 * sv.x;  pP.y += p1 * sv.y;  pP.z += p1 * sv.z;  pP.w += p1 * sv.w;
    qq.x += p2 * sv.x;  qq.y += p2 * sv.y;  qq.z += p2 * sv.z;  qq.w += p2 * sv.w;
  }
  // store exp-transformed score bases (shared-exp tanh trick)
  float4 eA, eP;
  eA.x = exp2f(K2 * pA.x); eA.y = exp2f(K2 * pA.y);
  eA.z = exp2f(K2 * pA.z); eA.w = exp2f(K2 * pA.w);
  eP.x = exp2f(K2 * pP.x); eP.y = exp2f(K2 * pP.y);
  eP.z = exp2f(K2 * pP.z); eP.w = exp2f(K2 * pP.w);
  int o = b * 8192 + hh * 64 + s0;
  *(float4*)&ws[WS_PREA + o] = eA;
  *(float4*)&ws[WS_PREP + o] = eP;
  *(float4*)&ws[WS_Q + o]    = qq;
}

// ---------------- main recurrence: 1 block/batch, 1024 thr, 64 steps ----
// 16 waves (4/SIMD). 88 array floats/thread (fits 128 VGPR). No libm calls.
// All reductions DPP; hot tanh = 1 - 2*rcp(EA*F + 1) (1 transcendental/elem).
__global__ __launch_bounds__(1024) void drl4tsp_main(
    const float* __restrict__ statics, const float* __restrict__ x0,
    const float* __restrict__ whh, const float* __restrict__ attn_W,
    const float* __restrict__ bhh_g, const float* __restrict__ attn_v,
    const float* __restrict__ ptr_v, const float* __restrict__ ws,
    float* __restrict__ out) {
  __shared__ __align__(16) float h_lds[160];   // PADH layout
  __shared__ float u3f[160];                   // SW layout: exp2(K2*u3[h])
  __shared__ float u2f[160];                   // SW layout: exp2(K2*u2[h])
  __shared__ float av2s[160];                  // SW: 2*attn_v
  __shared__ float pv2s[160];                  // SW: 2*ptr_v
  __shared__ float a_lds[64];
  __shared__ float l_lds[64];
  __shared__ float stt[128];

  const int b    = blockIdx.x;
  const int t    = threadIdx.x;
  const int lane = t & 63;
  const int g    = t >> 3;   // 0..127 row (matvec map)
  const int o    = t & 7;    // k/s octant
  const int s    = t >> 4;   // 0..63 column (score map)
  const int hg   = t & 15;   // h-group of 8

  // ---- register-resident weights (88 floats) ----
  float wr0[16], wr1[16], wr2[16], w3r[16];
  {
    const float4* pr = (const float4*)(whh + g * 128 + o * 16);
    const float4* pz = (const float4*)(whh + (128 + g) * 128 + o * 16);
    const float4* pn = (const float4*)(whh + (256 + g) * 128 + o * 16);
    const float4* p3 = (const float4*)(attn_W + g * 384 + 256 + o * 16);
#pragma unroll
    for (int i = 0; i < 4; ++i) {
      float4 a = pr[i], c = pz[i], d = pn[i], e = p3[i];
      wr0[4*i] = a.x; wr0[4*i+1] = a.y; wr0[4*i+2] = a.z; wr0[4*i+3] = a.w;
      wr1[4*i] = c.x; wr1[4*i+1] = c.y; wr1[4*i+2] = c.z; wr1[4*i+3] = c.w;
      wr2[4*i] = d.x; wr2[4*i+1] = d.y; wr2[4*i+2] = d.z; wr2[4*i+3] = d.w;
      w3r[4*i] = e.x; w3r[4*i+1] = e.y; w3r[4*i+2] = e.z; w3r[4*i+3] = e.w;
    }
  }
  float qr[8];
  {
    const float4* pq = (const float4*)(ws + WS_Q + b * 8192 + g * 64 + o * 8);
    float4 v0 = pq[0], v1 = pq[1];
    qr[0]=v0.x; qr[1]=v0.y; qr[2]=v0.z; qr[3]=v0.w;
    qr[4]=v1.x; qr[5]=v1.y; qr[6]=v1.z; qr[7]=v1.w;
  }
  float pa[8], pp[8], cav = 0.f, cpv = 0.f;
#pragma unroll
  for (int i = 0; i < 8; ++i) {
    int h = hg * 8 + i;
    pa[i] = ws[WS_PREA + b * 8192 + h * 64 + s];
    pp[i] = ws[WS_PREP + b * 8192 + h * 64 + s];
    cav += attn_v[h];
    cpv += ptr_v[h];
  }
  const float* Mm = ws + WS_M;
  const float* Cc = ws + WS_C;
  const float mR0 = Mm[g * 2],       mR1 = Mm[g * 2 + 1];
  const float cRt = Cc[g] + bhh_g[g];
  const float mZ0 = Mm[(128+g) * 2], mZ1 = Mm[(128+g) * 2 + 1];
  const float cZt = Cc[128 + g] + bhh_g[128 + g];
  const float mN0 = Mm[(256+g) * 2], mN1 = Mm[(256+g) * 2 + 1];
  const float cN0 = Cc[256 + g],     bN  = bhh_g[256 + g];

  if (t < 128) {
    stt[t] = statics[b * 128 + t];
    av2s[SW(t)] = 2.0f * attn_v[t];
    pv2s[SW(t)] = 2.0f * ptr_v[t];
  }
  __syncthreads();

  float hreg = 0.f, ghr = 0.f, ghz = 0.f, ghn = 0.f;
  float d0 = x0[0], d1 = x0[1];

  for (int step = 0; step < 64; ++step) {
    // ---- P1: GRU gates (pointwise; gh carried from prev P2) ----
    {
      float r = RCP(1.f + EXP2(-K1 * (mR0*d0 + mR1*d1 + cRt + ghr)));
      float z = RCP(1.f + EXP2(-K1 * (mZ0*d0 + mZ1*d1 + cZt + ghz)));
      float xn = mN0*d0 + mN1*d1 + cN0 + r * (ghn + bN);
      float n = 1.f - 2.f * RCP(EXP2(K2 * xn) + 1.f);   // tanh(xn)
      hreg = (1.f - z) * n + z * hreg;
      if (o == 0) h_lds[PADH(g)] = hreg;
    }
    __syncthreads();                                   // A
    // ---- P2: u3 = W3@h  +  next-step gh = whh@h (fused reads) ----
    {
      float u3 = 0.f, sr = 0.f, sz = 0.f, sn = 0.f;
#pragma unroll
      for (int k4 = 0; k4 < 4; ++k4) {
        float4 hv = *(const float4*)&h_lds[o * 20 + k4 * 4];
        int k = k4 * 4;
        u3 += w3r[k]*hv.x + w3r[k+1]*hv.y + w3r[k+2]*hv.z + w3r[k+3]*hv.w;
        sr += wr0[k]*hv.x + wr0[k+1]*hv.y + wr0[k+2]*hv.z + wr0[k+3]*hv.w;
        sz += wr1[k]*hv.x + wr1[k+1]*hv.y + wr1[k+2]*hv.z + wr1[k+3]*hv.w;
        sn += wr2[k]*hv.x + wr2[k+1]*hv.y + wr2[k+2]*hv.z + wr2[k+3]*hv.w;
      }
      ghr = sum8(sr); ghz = sum8(sz); ghn = sum8(sn);
      u3 = sum8(u3);
      if (o == 0) u3f[SW(g)] = EXP2(K2 * u3);
    }
    __syncthreads();                                   // B
    // ---- P3: a[s] = cav - sum_h av2[h]*rcp(EA[h,s]*F3[h]+1) ----
    {
      float acc = cav;
#pragma unroll
      for (int i = 0; i < 8; ++i) {
        int sw = SW(hg * 8 + i);
        acc -= av2s[sw] * RCP(pa[i] * u3f[sw] + 1.f);
      }
      acc = sum16(acc);
      if (hg == 0) a_lds[s] = acc;
    }
    __syncthreads();                                   // C
    // ---- P4: softmax (wave-redundant) + u2 = Q@attns ----
    {
      float a = a_lds[lane];
      float m = max64(a);
      float e = EXP2(K1 * (a - m));
      float p = 0.f;
#pragma unroll
      for (int i = 0; i < 8; ++i) p += qr[i] * __shfl(e, o * 8 + i);
      float sum = sum64(e);           // issued after gathers (independent)
      p *= RCP(sum);
      p = sum8(p);
      if (o == 0) u2f[SW(g)] = EXP2(K2 * p);
    }
    __syncthreads();                                   // D
    // ---- P5: l[s] = cpv - sum_h pv2[h]*rcp(EP[h,s]*F2[h]+1) ----
    {
      float acc = cpv;
#pragma unroll
      for (int i = 0; i < 8; ++i) {
        int sw = SW(hg * 8 + i);
        acc -= pv2s[sw] * RCP(pp[i] * u2f[sw] + 1.f);
      }
      acc = sum16(acc);
      if (hg == 0) l_lds[s] = acc;
    }
    __syncthreads();                                   // E
    // ---- P6: argmax (first-index tiebreak) + logp + dec feedback ----
    {
      float L = l_lds[lane];
      float v = L;
      int idx = lane;
#define AMX(CTRL) { float ov = dppf<CTRL>(v); int oi = dppi<CTRL>(idx); \
      if (ov > v || (ov == v && oi < idx)) { v = ov; idx = oi; } }
      AMX(0xB1) AMX(0x4E) AMX(0x141) AMX(0x128)
#undef AMX
      { float ov = __shfl_xor(v, 16); int oi = __shfl_xor(idx, 16);
        if (ov > v || (ov == v && oi < idx)) { v = ov; idx = oi; } }
      { float ov = __shfl_xor(v, 32); int oi = __shfl_xor(idx, 32);
        if (ov > v || (ov == v && oi < idx)) { v = ov; idx = oi; } }
      float e2 = EXP2(K1 * (L - v));
      float s3 = sum64(e2);
      if (t == 0) {
        out[b * 64 + step] = (float)idx;                       // tour_idx
        out[8192 + b * 64 + step] = -LN2 * __builtin_amdgcn_logf(s3);  // logp
      }
      d0 = stt[idx];                                   // uniform broadcast
      d1 = stt[64 + idx];
    }
    // no barrier: next write of each buffer is >=2 barriers downstream
  }
}

extern "C" void kernel_launch(void* const* d_in, const int* in_sizes, int n_in,
                              void* d_out, int out_size, void* d_ws, size_t ws_size,
                              hipStream_t stream) {
  const float* statics  = (const float*)d_in[0];
  const float* dynamics = (const float*)d_in[1];
  const float* x0       = (const float*)d_in[2];
  const float* sw       = (const float*)d_in[3];
  const float* sb       = (const float*)d_in[4];
  const float* dw       = (const float*)d_in[5];
  const float* db       = (const float*)d_in[6];
  const float* decw     = (const float*)d_in[7];
  const float* decb     = (const float*)d_in[8];
  const float* wih      = (const float*)d_in[9];
  const float* whh      = (const float*)d_in[10];
  const float* bih      = (const float*)d_in[11];
  const float* bhh      = (const float*)d_in[12];
  const float* attn_v   = (const float*)d_in[13];
  const float* attn_W   = (const float*)d_in[14];
  const float* ptr_v    = (const float*)d_in[15];
  const float* ptr_W    = (const float*)d_in[16];
  float* ws  = (float*)d_ws;
  float* out = (float*)d_out;

  hipLaunchKernelGGL(prep_small, dim3(2), dim3(256), 0, stream,
                     wih, decw, decb, bih, ws);
  hipLaunchKernelGGL(prep_big, dim3(1024), dim3(256), 0, stream,
                     statics, dynamics, sw, sb, dw, db, attn_W, ptr_W, ws);
  hipLaunchKernelGGL(drl4tsp_main, dim3(128), dim3(1024), 0, stream,
                     statics, x0, whh, attn_W, bhh, attn_v, ptr_v, ws, out);
}

// Round 5
// 350.470 us; speedup vs baseline: 1.0008x; 1.0008x over previous
//
#include <hip/hip_runtime.h>
#include <math.h>

// Problem dims (fixed): B=128, S=64, H=128, STATIC=DYNAMIC=2
// Outputs: tour_idx [B,S] (as f32), tour_logp [B,S] -> d_out 16384 f32

#define K1  1.44269504088896340736f   // log2(e)
#define K2  2.88539008177792681472f   // 2*log2(e)
#define LN2 0.69314718055994530942f

// ---------------- ws layout (float offsets) ----------------
#define WS_M     0                       // [384][2]   M = wih @ decoder_w
#define WS_C     768                     // [384]      c = wih @ decoder_b + bih
#define WS_PREA  1152                    // [B][128][64] EA = exp2(K2*(W1@sh + W2@dh))
#define WS_PREP  (WS_PREA + 128*8192)    // [B][128][64] EP = exp2(K2*(P1@sh))
#define WS_Q     (WS_PREP + 128*8192)    // [B][128][64] Q  = P2@sh

// LDS swizzles (conflict-free for the specific read patterns)
#define SW(h)   ((h) + ((h) >> 2))            // 128-vec read at stride 8
#define PADH(h) ((((h) >> 4) * 20) + ((h) & 15))  // 128-vec float4 read, 16-chunks

// ---- DPP cross-lane (VALU-speed; rows=16 lanes) ----
template <int CTRL>
__device__ __forceinline__ float dppf(float x) {
  int xi = __builtin_bit_cast(int, x);
  return __builtin_bit_cast(float,
      __builtin_amdgcn_update_dpp(xi, xi, CTRL, 0xF, 0xF, false));
}
template <int CTRL>
__device__ __forceinline__ int dppi(int x) {
  return __builtin_amdgcn_update_dpp(x, x, CTRL, 0xF, 0xF, false);
}
// 0xB1=quad xor1, 0x4E=quad xor2, 0x141=row_half_mirror, 0x128=row_ror:8
__device__ __forceinline__ float sum8(float x) {   // 8 consecutive lanes
  x += dppf<0xB1>(x); x += dppf<0x4E>(x); x += dppf<0x141>(x); return x;
}
__device__ __forceinline__ float sum16(float x) {  // 16 consecutive lanes
  x += dppf<0xB1>(x); x += dppf<0x4E>(x); x += dppf<0x141>(x); x += dppf<0x128>(x);
  return x;
}
__device__ __forceinline__ float sum64(float x) {
  x = sum16(x); x += __shfl_xor(x, 16); x += __shfl_xor(x, 32); return x;
}
__device__ __forceinline__ float max64(float x) {
  x = fmaxf(x, dppf<0xB1>(x)); x = fmaxf(x, dppf<0x4E>(x));
  x = fmaxf(x, dppf<0x141>(x)); x = fmaxf(x, dppf<0x128>(x));
  x = fmaxf(x, __shfl_xor(x, 16)); x = fmaxf(x, __shfl_xor(x, 32)); return x;
}
#define RCP(x)  __builtin_amdgcn_rcpf(x)
#define EXP2(x) __builtin_amdgcn_exp2f(x)

// ---------------- tiny precompute: GRU input-path folding ----------------
__global__ __launch_bounds__(256) void prep_small(
    const float* __restrict__ wih, const float* __restrict__ decw,
    const float* __restrict__ decb, const float* __restrict__ bih,
    float* __restrict__ ws) {
  int gid = blockIdx.x * 256 + threadIdx.x;
  if (gid < 384) {
    float m0 = 0.f, m1 = 0.f, cc = 0.f;
    for (int k = 0; k < 128; ++k) {
      float w = wih[gid * 128 + k];
      m0 += w * decw[k * 2 + 0];
      m1 += w * decw[k * 2 + 1];
      cc += w * decb[k];
    }
    ws[WS_M + gid * 2 + 0] = m0;
    ws[WS_M + gid * 2 + 1] = m1;
    ws[WS_C + gid] = cc + bih[gid];
  }
}

// ---------------- big precompute: EA / EP / Q per batch ------------------
__global__ __launch_bounds__(256) void prep_big(
    const float* __restrict__ statics, const float* __restrict__ dynamics,
    const float* __restrict__ sw, const float* __restrict__ sb,
    const float* __restrict__ dw, const float* __restrict__ db,
    const float* __restrict__ attn_W, const float* __restrict__ ptr_W,
    float* __restrict__ ws) {
  __shared__ __align__(16) float sh[128 * 64];
  __shared__ __align__(16) float dh[128 * 64];
  __shared__ float st[128];
  __shared__ float dy[128];
  int b = blockIdx.x >> 3;
  int hq = blockIdx.x & 7;
  int t = threadIdx.x;
  if (t < 128) st[t] = statics[b * 128 + t];
  else         dy[t - 128] = dynamics[b * 128 + (t - 128)];
  __syncthreads();
  for (int e = t; e < 8192; e += 256) {
    int h = e >> 6, s = e & 63;
    sh[e] = sw[h * 2 + 0] * st[s] + sw[h * 2 + 1] * st[64 + s] + sb[h];
    dh[e] = dw[h * 2 + 0] * dy[s] + dw[h * 2 + 1] * dy[64 + s] + db[h];
  }
  __syncthreads();
  int hh = hq * 16 + (t >> 4);
  int s0 = (t & 15) * 4;
  float4 pA = {0, 0, 0, 0}, pP = {0, 0, 0, 0}, qq = {0, 0, 0, 0};
  for (int k = 0; k < 128; ++k) {
    float4 sv = *(const float4*)&sh[k * 64 + s0];
    float4 dv = *(const float4*)&dh[k * 64 + s0];
    float w1 = attn_W[hh * 384 + k];
    float w2 = attn_W[hh * 384 + 128 + k];
    float p1 = ptr_W[hh * 256 + k];
    float p2 = ptr_W[hh * 256 + 128 + k];
    pA.x += w1 * sv.x + w2 * dv.x;  pA.y += w1 * sv.y + w2 * dv.y;
    pA.z += w1 * sv.z + w2 * dv.z;  pA.w += w1 * sv.w + w2 * dv.w;
    pP.x += p1 * sv.x;  pP.y += p1 * sv.y;  pP.z += p1 * sv.z;  pP.w += p1 * sv.w;
    qq.x += p2 * sv.x;  qq.y += p2 * sv.y;  qq.z += p2 * sv.z;  qq.w += p2 * sv.w;
  }
  // store exp-transformed score bases (shared-exp tanh trick)
  float4 eA, eP;
  eA.x = exp2f(K2 * pA.x); eA.y = exp2f(K2 * pA.y);
  eA.z = exp2f(K2 * pA.z); eA.w = exp2f(K2 * pA.w);
  eP.x = exp2f(K2 * pP.x); eP.y = exp2f(K2 * pP.y);
  eP.z = exp2f(K2 * pP.z); eP.w = exp2f(K2 * pP.w);
  int o = b * 8192 + hh * 64 + s0;
  *(float4*)&ws[WS_PREA + o] = eA;
  *(float4*)&ws[WS_PREP + o] = eP;
  *(float4*)&ws[WS_Q + o]    = qq;
}

// ---------------- main recurrence: 1 block/batch, 1024 thr, 64 steps ----
// 16 waves, EXPLICIT 4 waves/EU -> VGPR cap 128 (88 array floats resident,
// no spill). No libm calls; all reductions DPP; hot tanh = 1-2*rcp(EA*F+1).
__global__ __launch_bounds__(1024, 4) void drl4tsp_main(
    const float* __restrict__ statics, const float* __restrict__ x0,
    const float* __restrict__ whh, const float* __restrict__ attn_W,
    const float* __restrict__ bhh_g, const float* __restrict__ attn_v,
    const float* __restrict__ ptr_v, const float* __restrict__ ws,
    float* __restrict__ out) {
  __shared__ __align__(16) float h_lds[160];   // PADH layout
  __shared__ float u3f[160];                   // SW layout: exp2(K2*u3[h])
  __shared__ float u2f[160];                   // SW layout: exp2(K2*u2[h])
  __shared__ float av2s[160];                  // SW: 2*attn_v
  __shared__ float pv2s[160];                  // SW: 2*ptr_v
  __shared__ float a_lds[64];
  __shared__ float l_lds[64];
  __shared__ float stt[128];

  const int b    = blockIdx.x;
  const int t    = threadIdx.x;
  const int lane = t & 63;
  const int g    = t >> 3;   // 0..127 row (matvec map)
  const int o    = t & 7;    // k/s octant
  const int s    = t >> 4;   // 0..63 column (score map)
  const int hg   = t & 15;   // h-group of 8

  // ---- register-resident weights (88 floats) ----
  float wr0[16], wr1[16], wr2[16], w3r[16];
  {
    const float4* pr = (const float4*)(whh + g * 128 + o * 16);
    const float4* pz = (const float4*)(whh + (128 + g) * 128 + o * 16);
    const float4* pn = (const float4*)(whh + (256 + g) * 128 + o * 16);
    const float4* p3 = (const float4*)(attn_W + g * 384 + 256 + o * 16);
#pragma unroll
    for (int i = 0; i < 4; ++i) {
      float4 a = pr[i], c = pz[i], d = pn[i], e = p3[i];
      wr0[4*i] = a.x; wr0[4*i+1] = a.y; wr0[4*i+2] = a.z; wr0[4*i+3] = a.w;
      wr1[4*i] = c.x; wr1[4*i+1] = c.y; wr1[4*i+2] = c.z; wr1[4*i+3] = c.w;
      wr2[4*i] = d.x; wr2[4*i+1] = d.y; wr2[4*i+2] = d.z; wr2[4*i+3] = d.w;
      w3r[4*i] = e.x; w3r[4*i+1] = e.y; w3r[4*i+2] = e.z; w3r[4*i+3] = e.w;
    }
  }
  float qr[8];
  {
    const float4* pq = (const float4*)(ws + WS_Q + b * 8192 + g * 64 + o * 8);
    float4 v0 = pq[0], v1 = pq[1];
    qr[0]=v0.x; qr[1]=v0.y; qr[2]=v0.z; qr[3]=v0.w;
    qr[4]=v1.x; qr[5]=v1.y; qr[6]=v1.z; qr[7]=v1.w;
  }
  float pa[8], pp[8], cav = 0.f, cpv = 0.f;
#pragma unroll
  for (int i = 0; i < 8; ++i) {
    int h = hg * 8 + i;
    pa[i] = ws[WS_PREA + b * 8192 + h * 64 + s];
    pp[i] = ws[WS_PREP + b * 8192 + h * 64 + s];
    cav += attn_v[h];
    cpv += ptr_v[h];
  }
  const float* Mm = ws + WS_M;
  const float* Cc = ws + WS_C;
  const float mR0 = Mm[g * 2],       mR1 = Mm[g * 2 + 1];
  const float cRt = Cc[g] + bhh_g[g];
  const float mZ0 = Mm[(128+g) * 2], mZ1 = Mm[(128+g) * 2 + 1];
  const float cZt = Cc[128 + g] + bhh_g[128 + g];
  const float mN0 = Mm[(256+g) * 2], mN1 = Mm[(256+g) * 2 + 1];
  const float cN0 = Cc[256 + g],     bN  = bhh_g[256 + g];

  if (t < 128) {
    stt[t] = statics[b * 128 + t];
    av2s[SW(t)] = 2.0f * attn_v[t];
    pv2s[SW(t)] = 2.0f * ptr_v[t];
  }
  __syncthreads();

  float hreg = 0.f, ghr = 0.f, ghz = 0.f, ghn = 0.f;
  float d0 = x0[0], d1 = x0[1];

  for (int step = 0; step < 64; ++step) {
    // ---- P1: GRU gates (pointwise; gh carried from prev P2) ----
    {
      float r = RCP(1.f + EXP2(-K1 * (mR0*d0 + mR1*d1 + cRt + ghr)));
      float z = RCP(1.f + EXP2(-K1 * (mZ0*d0 + mZ1*d1 + cZt + ghz)));
      float xn = mN0*d0 + mN1*d1 + cN0 + r * (ghn + bN);
      float n = 1.f - 2.f * RCP(EXP2(K2 * xn) + 1.f);   // tanh(xn)
      hreg = (1.f - z) * n + z * hreg;
      if (o == 0) h_lds[PADH(g)] = hreg;
    }
    __syncthreads();                                   // A
    // ---- P2: u3 = W3@h  +  next-step gh = whh@h (fused reads) ----
    {
      float u3 = 0.f, sr = 0.f, sz = 0.f, sn = 0.f;
#pragma unroll
      for (int k4 = 0; k4 < 4; ++k4) {
        float4 hv = *(const float4*)&h_lds[o * 20 + k4 * 4];
        int k = k4 * 4;
        u3 += w3r[k]*hv.x + w3r[k+1]*hv.y + w3r[k+2]*hv.z + w3r[k+3]*hv.w;
        sr += wr0[k]*hv.x + wr0[k+1]*hv.y + wr0[k+2]*hv.z + wr0[k+3]*hv.w;
        sz += wr1[k]*hv.x + wr1[k+1]*hv.y + wr1[k+2]*hv.z + wr1[k+3]*hv.w;
        sn += wr2[k]*hv.x + wr2[k+1]*hv.y + wr2[k+2]*hv.z + wr2[k+3]*hv.w;
      }
      ghr = sum8(sr); ghz = sum8(sz); ghn = sum8(sn);
      u3 = sum8(u3);
      if (o == 0) u3f[SW(g)] = EXP2(K2 * u3);
    }
    __syncthreads();                                   // B
    // ---- P3: a[s] = cav - sum_h av2[h]*rcp(EA[h,s]*F3[h]+1) ----
    {
      float acc = cav;
#pragma unroll
      for (int i = 0; i < 8; ++i) {
        int sw = SW(hg * 8 + i);
        acc -= av2s[sw] * RCP(pa[i] * u3f[sw] + 1.f);
      }
      acc = sum16(acc);
      if (hg == 0) a_lds[s] = acc;
    }
    __syncthreads();                                   // C
    // ---- P4: softmax (wave-redundant) + u2 = Q@attns ----
    {
      float a = a_lds[lane];
      float m = max64(a);
      float e = EXP2(K1 * (a - m));
      float p = 0.f;
#pragma unroll
      for (int i = 0; i < 8; ++i) p += qr[i] * __shfl(e, o * 8 + i);
      float sum = sum64(e);           // issued after gathers (independent)
      p *= RCP(sum);
      p = sum8(p);
      if (o == 0) u2f[SW(g)] = EXP2(K2 * p);
    }
    __syncthreads();                                   // D
    // ---- P5: l[s] = cpv - sum_h pv2[h]*rcp(EP[h,s]*F2[h]+1) ----
    {
      float acc = cpv;
#pragma unroll
      for (int i = 0; i < 8; ++i) {
        int sw = SW(hg * 8 + i);
        acc -= pv2s[sw] * RCP(pp[i] * u2f[sw] + 1.f);
      }
      acc = sum16(acc);
      if (hg == 0) l_lds[s] = acc;
    }
    __syncthreads();                                   // E
    // ---- P6: argmax (first-index tiebreak) + logp + dec feedback ----
    {
      float L = l_lds[lane];
      float v = L;
      int idx = lane;
#define AMX(CTRL) { float ov = dppf<CTRL>(v); int oi = dppi<CTRL>(idx); \
      if (ov > v || (ov == v && oi < idx)) { v = ov; idx = oi; } }
      AMX(0xB1) AMX(0x4E) AMX(0x141) AMX(0x128)
#undef AMX
      { float ov = __shfl_xor(v, 16); int oi = __shfl_xor(idx, 16);
        if (ov > v || (ov == v && oi < idx)) { v = ov; idx = oi; } }
      { float ov = __shfl_xor(v, 32); int oi = __shfl_xor(idx, 32);
        if (ov > v || (ov == v && oi < idx)) { v = ov; idx = oi; } }
      float e2 = EXP2(K1 * (L - v));
      float s3 = sum64(e2);
      if (t == 0) {
        out[b * 64 + step] = (float)idx;                       // tour_idx
        out[8192 + b * 64 + step] = -LN2 * __builtin_amdgcn_logf(s3);  // logp
      }
      d0 = stt[idx];                                   // uniform broadcast
      d1 = stt[64 + idx];
    }
    // no barrier: next write of each buffer is >=2 barriers downstream
  }
}

extern "C" void kernel_launch(void* const* d_in, const int* in_sizes, int n_in,
                              void* d_out, int out_size, void* d_ws, size_t ws_size,
                              hipStream_t stream) {
  const float* statics  = (const float*)d_in[0];
  const float* dynamics = (const float*)d_in[1];
  const float* x0       = (const float*)d_in[2];
  const float* sw       = (const float*)d_in[3];
  const float* sb       = (const float*)d_in[4];
  const float* dw       = (const float*)d_in[5];
  const float* db       = (const float*)d_in[6];
  const float* decw     = (const float*)d_in[7];
  const float* decb     = (const float*)d_in[8];
  const float* wih      = (const float*)d_in[9];
  const float* whh      = (const float*)d_in[10];
  const float* bih      = (const float*)d_in[11];
  const float* bhh      = (const float*)d_in[12];
  const float* attn_v   = (const float*)d_in[13];
  const float* attn_W   = (const float*)d_in[14];
  const float* ptr_v    = (const float*)d_in[15];
  const float* ptr_W    = (const float*)d_in[16];
  float* ws  = (float*)d_ws;
  float* out = (float*)d_out;

  hipLaunchKernelGGL(prep_small, dim3(2), dim3(256), 0, stream,
                     wih, decw, decb, bih, ws);
  hipLaunchKernelGGL(prep_big, dim3(1024), dim3(256), 0, stream,
                     statics, dynamics, sw, sb, dw, db, attn_W, ptr_W, ws);
  hipLaunchKernelGGL(drl4tsp_main, dim3(128), dim3(1024), 0, stream,
                     statics, x0, whh, attn_W, bhh, attn_v, ptr_v, ws, out);
}